// Round 1
// baseline (377.972 us; speedup 1.0000x reference)
//
#include <hip/hip_runtime.h>
#include <hip/hip_bf16.h>
#include <math.h>

// Problem: x shape (64, 256, 56, 56) fp32.
// Per-sample min/max -> fake quant -> dequant -> clip(0,6).
// Sample size = 256*56*56 = 802816 floats = 200704 float4.

#define SAMPLE_V4   200704          // float4 per sample
#define BPS_R       49              // reduction blocks per sample
#define V4_PER_BLK_R 4096           // 200704 / 49
#define BPS_E       98              // elementwise blocks per sample
#define V4_PER_BLK_E 2048           // 200704 / 98
#define NSAMPLES    64

__global__ __launch_bounds__(256) void qr_reduce(const float4* __restrict__ x,
                                                 float* __restrict__ pmin,
                                                 float* __restrict__ pmax) {
    const int s = blockIdx.x / BPS_R;
    const int b = blockIdx.x % BPS_R;
    const float4* base = x + (size_t)s * SAMPLE_V4 + (size_t)b * V4_PER_BLK_R;

    float mn = INFINITY, mx = -INFINITY;
    // 4096 float4 per block, 256 threads -> 16 iters, fully coalesced.
    for (int i = threadIdx.x; i < V4_PER_BLK_R; i += 256) {
        float4 v = base[i];
        mn = fminf(mn, fminf(fminf(v.x, v.y), fminf(v.z, v.w)));
        mx = fmaxf(mx, fmaxf(fmaxf(v.x, v.y), fmaxf(v.z, v.w)));
    }
    // wave64 shuffle reduce
    #pragma unroll
    for (int off = 32; off > 0; off >>= 1) {
        mn = fminf(mn, __shfl_down(mn, off, 64));
        mx = fmaxf(mx, __shfl_down(mx, off, 64));
    }
    __shared__ float smn[4], smx[4];
    const int wave = threadIdx.x >> 6;
    if ((threadIdx.x & 63) == 0) { smn[wave] = mn; smx[wave] = mx; }
    __syncthreads();
    if (threadIdx.x == 0) {
        mn = fminf(fminf(smn[0], smn[1]), fminf(smn[2], smn[3]));
        mx = fmaxf(fmaxf(smx[0], smx[1]), fmaxf(smx[2], smx[3]));
        pmin[blockIdx.x] = mn;
        pmax[blockIdx.x] = mx;
    }
}

__global__ __launch_bounds__(64) void qr_finalize(const float* __restrict__ pmin,
                                                  const float* __restrict__ pmax,
                                                  float* __restrict__ params) {
    const int s = blockIdx.x;
    const int t = threadIdx.x;
    float mn = (t < BPS_R) ? pmin[s * BPS_R + t] : INFINITY;
    float mx = (t < BPS_R) ? pmax[s * BPS_R + t] : -INFINITY;
    #pragma unroll
    for (int off = 32; off > 0; off >>= 1) {
        mn = fminf(mn, __shfl_down(mn, off, 64));
        mx = fmaxf(mx, __shfl_down(mx, off, 64));
    }
    if (t == 0) {
        const float rng = mx - mn;
        params[s * 3 + 0] = mn;                   // m
        params[s * 3 + 1] = rng * (1.0f / 254.0f); // scale
        params[s * 3 + 2] = 254.0f / rng;          // inverse scale
    }
}

__device__ __forceinline__ float qr_apply1(float x, float m, float sc, float inv) {
    // reference: round(254*(x-m)/rng - 127) -> k; y = (k+127)*rng/254 + m; clip(0,6)
    float k = rintf((x - m) * inv - 127.0f);       // half-to-even, matches jnp.round
    float y = fmaf(k + 127.0f, sc, m);
    return fminf(fmaxf(y, 0.0f), 6.0f);
}

__global__ __launch_bounds__(256) void qr_apply(const float4* __restrict__ x,
                                                float4* __restrict__ y,
                                                const float* __restrict__ params) {
    const int s = blockIdx.x / BPS_E;
    const int b = blockIdx.x % BPS_E;
    const float m   = params[s * 3 + 0];
    const float sc  = params[s * 3 + 1];
    const float inv = params[s * 3 + 2];
    const size_t off = (size_t)s * SAMPLE_V4 + (size_t)b * V4_PER_BLK_E;
    const float4* xb = x + off;
    float4* yb = y + off;
    // 2048 float4 per block, 256 threads -> 8 iters
    for (int i = threadIdx.x; i < V4_PER_BLK_E; i += 256) {
        float4 v = xb[i];
        v.x = qr_apply1(v.x, m, sc, inv);
        v.y = qr_apply1(v.y, m, sc, inv);
        v.z = qr_apply1(v.z, m, sc, inv);
        v.w = qr_apply1(v.w, m, sc, inv);
        yb[i] = v;
    }
}

extern "C" void kernel_launch(void* const* d_in, const int* in_sizes, int n_in,
                              void* d_out, int out_size, void* d_ws, size_t ws_size,
                              hipStream_t stream) {
    const float* x = (const float*)d_in[0];
    float* out = (float*)d_out;

    // ws layout (floats): pmin[64*49] | pmax[64*49] | params[64*3]
    float* pmin   = (float*)d_ws;
    float* pmax   = pmin + NSAMPLES * BPS_R;
    float* params = pmax + NSAMPLES * BPS_R;

    qr_reduce<<<NSAMPLES * BPS_R, 256, 0, stream>>>((const float4*)x, pmin, pmax);
    qr_finalize<<<NSAMPLES, 64, 0, stream>>>(pmin, pmax, params);
    qr_apply<<<NSAMPLES * BPS_E, 256, 0, stream>>>((const float4*)x, (float4*)out, params);
}

// Round 3
// 370.624 us; speedup vs baseline: 1.0198x; 1.0198x over previous
//
#include <hip/hip_runtime.h>
#include <hip/hip_bf16.h>
#include <math.h>

// x shape (64, 256, 56, 56) fp32. Per-sample min/max -> fake quant -> dequant -> ReLU6.
// Sample = 802816 floats = 200704 float4.

#define SAMPLE_V4    200704
#define NSAMPLES     64
#define BPS_R        16              // reduce blocks per sample
#define V4_PER_BLK_R 12544           // 200704 / 16
#define BPS_E        98              // apply blocks per sample
#define V4_PER_BLK_E 2048            // 200704 / 98

typedef __attribute__((ext_vector_type(4))) float fvec4;   // native vector for builtins

__global__ __launch_bounds__(256) void qr_reduce(const float4* __restrict__ x,
                                                 float* __restrict__ pmin,
                                                 float* __restrict__ pmax) {
    const int s = blockIdx.x >> 4;          // / BPS_R
    const int b = blockIdx.x & (BPS_R - 1);
    const float4* base = x + (size_t)s * SAMPLE_V4 + (size_t)b * V4_PER_BLK_R;

    float mn = INFINITY, mx = -INFINITY;
    for (int i = threadIdx.x; i < V4_PER_BLK_R; i += 256) {   // 49 iters, coalesced
        float4 v = base[i];
        mn = fminf(mn, fminf(fminf(v.x, v.y), fminf(v.z, v.w)));
        mx = fmaxf(mx, fmaxf(fmaxf(v.x, v.y), fmaxf(v.z, v.w)));
    }
    #pragma unroll
    for (int off = 32; off > 0; off >>= 1) {
        mn = fminf(mn, __shfl_down(mn, off, 64));
        mx = fmaxf(mx, __shfl_down(mx, off, 64));
    }
    __shared__ float smn[4], smx[4];
    const int wave = threadIdx.x >> 6;
    if ((threadIdx.x & 63) == 0) { smn[wave] = mn; smx[wave] = mx; }
    __syncthreads();
    if (threadIdx.x == 0) {
        pmin[blockIdx.x] = fminf(fminf(smn[0], smn[1]), fminf(smn[2], smn[3]));
        pmax[blockIdx.x] = fmaxf(fmaxf(smx[0], smx[1]), fmaxf(smx[2], smx[3]));
    }
}

__device__ __forceinline__ float qr_apply1(float x, float m, float sc, float inv) {
    float k = rintf((x - m) * inv - 127.0f);       // half-to-even == jnp.round
    float y = fmaf(k + 127.0f, sc, m);
    return fminf(fmaxf(y, 0.0f), 6.0f);
}

__global__ __launch_bounds__(256) void qr_apply(const float4* __restrict__ x,
                                                float4* __restrict__ y,
                                                const float* __restrict__ pmin,
                                                const float* __restrict__ pmax) {
    const int s = blockIdx.x / BPS_E;
    const int b = blockIdx.x % BPS_E;

    // Per-block finalize: reduce this sample's 16 partials (reads hit L2/L3).
    __shared__ float sp[3];
    if (threadIdx.x < 64) {
        float mn = (threadIdx.x < BPS_R) ? pmin[s * BPS_R + threadIdx.x] : INFINITY;
        float mx = (threadIdx.x < BPS_R) ? pmax[s * BPS_R + threadIdx.x] : -INFINITY;
        #pragma unroll
        for (int off = 8; off > 0; off >>= 1) {
            mn = fminf(mn, __shfl_down(mn, off, 64));
            mx = fmaxf(mx, __shfl_down(mx, off, 64));
        }
        if (threadIdx.x == 0) {
            const float rng = mx - mn;
            sp[0] = mn;
            sp[1] = rng * (1.0f / 254.0f);
            sp[2] = 254.0f / rng;
        }
    }
    __syncthreads();
    const float m = sp[0], sc = sp[1], inv = sp[2];

    const size_t off = (size_t)s * SAMPLE_V4 + (size_t)b * V4_PER_BLK_E;
    const float4* xb = x + off;
    fvec4* yb = (fvec4*)(y + off);
    for (int i = threadIdx.x; i < V4_PER_BLK_E; i += 256) {    // 8 iters
        float4 v = xb[i];
        fvec4 o;
        o.x = qr_apply1(v.x, m, sc, inv);
        o.y = qr_apply1(v.y, m, sc, inv);
        o.z = qr_apply1(v.z, m, sc, inv);
        o.w = qr_apply1(v.w, m, sc, inv);
        __builtin_nontemporal_store(o, &yb[i]);    // don't evict x from L2/L3
    }
}

extern "C" void kernel_launch(void* const* d_in, const int* in_sizes, int n_in,
                              void* d_out, int out_size, void* d_ws, size_t ws_size,
                              hipStream_t stream) {
    const float* x = (const float*)d_in[0];
    float* out = (float*)d_out;

    float* pmin = (float*)d_ws;                 // 64*16 floats
    float* pmax = pmin + NSAMPLES * BPS_R;      // 64*16 floats

    qr_reduce<<<NSAMPLES * BPS_R, 256, 0, stream>>>((const float4*)x, pmin, pmax);
    qr_apply<<<NSAMPLES * BPS_E, 256, 0, stream>>>((const float4*)x, (float4*)out,
                                                   pmin, pmax);
}